// Round 5
// baseline (253.693 us; speedup 1.0000x reference)
//
#include <hip/hip_runtime.h>
#include <hip/hip_bf16.h>
#include <math.h>

#define N_NODES 50000
#define IN_DIM 256
#define OUT_DIM 128
#define NUM_HEADS 2
#define N_EDGES 800000
#define F (OUT_DIM*NUM_HEADS)   /* 256 */
#define SCAN_B 1024
#define N_SB ((N_NODES + SCAN_B - 1) / SCAN_B)   /* 49 */
#define LDSP 264                 /* 256 + 8 pad: 132-word row stride = 4 mod 32 banks */
#define CAP 128                  /* per-wave LDS edge chunk in k_agg */
#define N_COPIES 8               /* XCD-private histogram copies */
#define NBLK_H (N_EDGES / 256)   /* 3125 hist/scatter blocks, exactly 1 edge/thread */

typedef __bf16 bf16;
typedef __bf16 bf16x8 __attribute__((ext_vector_type(8)));
typedef float  f32x4  __attribute__((ext_vector_type(4)));
typedef unsigned short u16x8 __attribute__((ext_vector_type(8)));

// ---------------- K0: W -> Wt (bf16, transposed) + zero deg copies -------
__global__ void k_transpose(const float* __restrict__ W, bf16* __restrict__ Wt,
                            int* __restrict__ deg8) {
    int k = blockIdx.x;      // 0..IN_DIM-1
    int n = threadIdx.x;     // 0..F-1
    Wt[(size_t)n*IN_DIM + k] = (bf16)W[(size_t)k*F + n];
    int id = blockIdx.x * F + threadIdx.x;
    for (int i = id; i < N_COPIES * N_NODES; i += IN_DIM * F)
        deg8[i] = 0;
}

// ---------------- K1: standalone degree histogram + rank recording ------
// Dedicated kernel (round-3 post-mortem): inside k_gemm the staging barrier
// drained all in-flight atomics (vmcnt counts atomics) with only ~3
// blocks/CU to hide the latency, and the 77MB streaming traffic thrashed
// the histogram lines out of L2 -> invariant ~69us regardless of
// scope/privatization. Standalone: no barrier, deg8 L2-resident,
// thousands of independent waves -> pure atomic throughput.
// XCD-local copy via hardware XCC_ID + workgroup-scope (L2-local RMW;
// round-3 pass proves the RMW is at L2, so same-XCD blocks are safe).
// Atomic return = edge's rank within (xcd,node) -> atomic-free scatter.
__global__ __launch_bounds__(256) void k_hist(const int* __restrict__ src,
                                              int* __restrict__ deg8,
                                              unsigned char* __restrict__ rank,
                                              int* __restrict__ xcdtab) {
    unsigned xcc;
    asm volatile("s_getreg_b32 %0, hwreg(HW_REG_XCC_ID, 0, 4)" : "=s"(xcc));
    xcc &= (N_COPIES - 1);
    if (threadIdx.x == 0) xcdtab[blockIdx.x] = (int)xcc;
    int e = blockIdx.x * 256 + threadIdx.x;      // grid covers N_EDGES exactly
    int s = src[e];
    int r = __hip_atomic_fetch_add(&deg8[(size_t)xcc * N_NODES + s], 1,
                                   __ATOMIC_RELAXED, __HIP_MEMORY_SCOPE_WORKGROUP);
    rank[e] = (unsigned char)r;
}

// ---------------- K2: Wh = x @ W + b, fused s,t  (MFMA bf16) -------------
// Block: 64 rows x 256 cols, 4 waves. Full-K LDS A-tile, one staging barrier.
// Pure GEMM now (histogram un-fused into k_hist).
__global__ __launch_bounds__(256) void k_gemm(const float* __restrict__ X,
                                              const bf16* __restrict__ Wt,
                                              const float* __restrict__ Wb,
                                              const float* __restrict__ Av,
                                              bf16* __restrict__ Wh,
                                              float* __restrict__ s_arr,
                                              float* __restrict__ t_arr) {
    __shared__ bf16 As[64 * LDSP];
    __shared__ float sS[2][64], sT[2][64];
    int t = threadIdx.x;
    int wave = t >> 6, lane = t & 63;
    int quad = lane >> 4, l16 = lane & 15;
    int row0 = blockIdx.x * 64;
    int col0 = wave * 64;
    int h = wave >> 1;

    // staging: thread t, chunk i: row = 8i + (t>>5), cols (t&31)*8..+8
    {
        int rr = t >> 5;
        int cc = (t & 31) * 8;
        #pragma unroll
        for (int i = 0; i < 8; ++i) {
            int r = row0 + 8*i + rr;
            r = (r < N_NODES) ? r : (N_NODES - 1);
            const float* p = X + (size_t)r * IN_DIM + cc;
            f32x4 lo = *(const f32x4*)p;
            f32x4 hi = *(const f32x4*)(p + 4);
            bf16x8 pk;
            #pragma unroll
            for (int q = 0; q < 4; ++q) {
                pk[q]   = (bf16)lo[q];
                pk[q+4] = (bf16)hi[q];
            }
            *(bf16x8*)(As + (8*i + rr) * LDSP + cc) = pk;
        }
    }
    if (t < 128) { sS[t >> 6][t & 63] = 0.f; sT[t >> 6][t & 63] = 0.f; }
    __syncthreads();

    f32x4 acc[4][4] = {};
    #pragma unroll
    for (int ks = 0; ks < 8; ++ks) {
        int kb = ks * 32;
        bf16x8 bfrag[4];
        #pragma unroll
        for (int ni = 0; ni < 4; ++ni)
            bfrag[ni] = *(const bf16x8*)(Wt + (size_t)(col0 + ni*16 + l16)*IN_DIM
                                            + kb + quad*8);
        bf16x8 afrag[4];
        #pragma unroll
        for (int mi = 0; mi < 4; ++mi)
            afrag[mi] = *(const bf16x8*)(As + (mi*16 + l16)*LDSP + kb + quad*8);

        #pragma unroll
        for (int mi = 0; mi < 4; ++mi)
            #pragma unroll
            for (int ni = 0; ni < 4; ++ni)
                acc[mi][ni] = __builtin_amdgcn_mfma_f32_16x16x32_bf16(
                                  afrag[mi], bfrag[ni], acc[mi][ni], 0, 0, 0);
    }

    float bias_l[4], as_l[4], at_l[4];
    #pragma unroll
    for (int ni = 0; ni < 4; ++ni) {
        int c = col0 + ni*16 + l16;
        int d = c & (OUT_DIM - 1);
        bias_l[ni] = Wb[c];
        as_l[ni]   = Av[d];
        at_l[ni]   = Av[OUT_DIM + d];
    }

    // s,t partials from accumulators (C layout: col=lane&15, row=quad*4+reg)
    #pragma unroll
    for (int mi = 0; mi < 4; ++mi) {
        #pragma unroll
        for (int reg = 0; reg < 4; ++reg) {
            int rl = mi*16 + quad*4 + reg;
            float ps = 0.f, pt = 0.f;
            #pragma unroll
            for (int ni = 0; ni < 4; ++ni) {
                float val = acc[mi][ni][reg] + bias_l[ni];
                ps += val * as_l[ni];
                pt += val * at_l[ni];
            }
            #pragma unroll
            for (int m = 8; m >= 1; m >>= 1) {
                ps += __shfl_xor(ps, m);
                pt += __shfl_xor(pt, m);
            }
            if ((lane & 15) == 0) {
                atomicAdd(&sS[h][rl], ps);
                atomicAdd(&sT[h][rl], pt);
            }
        }
    }

    // repack acc -> As (bias added) for coalesced Wh stores
    __syncthreads();          // all waves done with As compute reads
    #pragma unroll
    for (int mi = 0; mi < 4; ++mi)
        #pragma unroll
        for (int ni = 0; ni < 4; ++ni) {
            int cc = col0 + ni*16 + l16;
            #pragma unroll
            for (int reg = 0; reg < 4; ++reg) {
                int rl = mi*16 + quad*4 + reg;
                As[rl*LDSP + cc] = (bf16)(acc[mi][ni][reg] + bias_l[ni]);
            }
        }
    __syncthreads();

    // coalesced write-out: 8 rounds x (ds_read_b128 + global_store_dwordx4)
    #pragma unroll
    for (int i = 0; i < 8; ++i) {
        int idx = i * 2048 + t * 8;     // 2048 elems (=8 rows) per round
        int row = idx >> 8;
        int cc  = idx & 255;
        bf16x8 v = *(const bf16x8*)(As + row*LDSP + cc);
        int grow = row0 + row;
        if (grow < N_NODES)
            *(bf16x8*)(Wh + (size_t)grow*F + cc) = v;
    }

    if (t < 128) {
        int hh = t >> 6, rl = t & 63;
        int n = row0 + rl;
        if (n < N_NODES) {
            s_arr[n*2 + hh] = sS[hh][rl];
            t_arr[n*2 + hh] = sT[hh][rl];
        }
    }
}

// ---------------- K4a: per-block exclusive scan (folds 8 deg copies) -----
// Also emits prefix8[n][c]: exclusive prefix of the 8 per-copy counts,
// consumed by the atomic-free k_scatter.
__global__ __launch_bounds__(SCAN_B) void k_scan_local(const int* __restrict__ deg8,
                                                       int* __restrict__ excl,
                                                       int* __restrict__ bsum,
                                                       unsigned short* __restrict__ prefix8) {
    __shared__ int lds[SCAN_B];
    int t = threadIdx.x;
    int i = blockIdx.x * SCAN_B + t;
    int v = 0;
    if (i < N_NODES) {
        u16x8 pf;
        int run = 0;
        #pragma unroll
        for (int c = 0; c < N_COPIES; ++c) {
            pf[c] = (unsigned short)run;
            run += deg8[(size_t)c * N_NODES + i];
        }
        v = run;
        *(u16x8*)(prefix8 + (size_t)i * 8) = pf;
    }
    lds[t] = v;
    __syncthreads();
    for (int off = 1; off < SCAN_B; off <<= 1) {
        int u = (t >= off) ? lds[t - off] : 0;
        __syncthreads();
        lds[t] += u;
        __syncthreads();
    }
    if (i < N_NODES) excl[i] = lds[t] - v;          // exclusive-local
    if (t == SCAN_B - 1) bsum[blockIdx.x] = lds[t]; // block total
}

// ---------------- K4b: finalize exclusive scan (folds block-sum scan) ----
__global__ __launch_bounds__(256) void k_scan_final(const int* __restrict__ excl,
                                                    const int* __restrict__ bsum,
                                                    int* __restrict__ row_start) {
    __shared__ int sboff[64];
    int t = threadIdx.x;
    if (t < 64) {
        int orig = (t < N_SB) ? bsum[t] : 0;
        int v = orig;
        #pragma unroll
        for (int off = 1; off < 64; off <<= 1) {
            int u = __shfl_up(v, off);
            if (t >= off) v += u;
        }
        sboff[t] = v - orig;
        if (t == 63 && blockIdx.x == 0) row_start[N_NODES] = v;
    }
    __syncthreads();
    int i = blockIdx.x * 256 + t;
    if (i < N_NODES)
        row_start[i] = excl[i] + sboff[i >> 10];
}

// ---------------- K5: ATOMIC-FREE scatter into CSR slots -----------------
// pos = row_start[s] + prefix8[s][c] + rank[e]; c = XCD that histogrammed
// edge e. k_hist block b owns edges [b*256, b*256+256) -> c = xcdtab[blockIdx].
__global__ __launch_bounds__(256) void k_scatter(const int* __restrict__ src,
                                                 const int* __restrict__ dst,
                                                 const unsigned char* __restrict__ rank,
                                                 const unsigned short* __restrict__ prefix8,
                                                 const int* __restrict__ row_start,
                                                 const int* __restrict__ xcdtab,
                                                 int* __restrict__ sorted_dst) {
    int e = blockIdx.x * 256 + threadIdx.x;      // grid covers N_EDGES exactly
    int c = xcdtab[blockIdx.x];                  // block-uniform scalar load
    int s = src[e];
    int pos = row_start[s] + (int)prefix8[(size_t)s * 8 + c] + (int)rank[e];
    sorted_dst[pos] = dst[e];
}

// ---------------- K6: fused softmax + gather+FMA aggregation -------------
// wave per node. Phase A (per CAP-chunk): lanes over edges compute
// p = exp(leaky(s+t)) (no max shift: softmax shift-invariant, |e| small)
// into wave-local LDS. Phase B: sub=lane>>5 edge-slot, cl=lane&31 col-group,
// gather Wh rows (16B/lane) + FMA, 8 edges/iter.
__global__ __launch_bounds__(256) void k_agg(const bf16* __restrict__ Wh,
                                             const float* __restrict__ s_arr,
                                             const float* __restrict__ t_arr,
                                             const int* __restrict__ row_start,
                                             const int* __restrict__ sdst,
                                             float* __restrict__ out) {
    __shared__ float sp0[4][CAP];
    __shared__ float sp1[4][CAP];
    __shared__ int   sd[4][CAP];
    int wave = threadIdx.x >> 6, lane = threadIdx.x & 63;
    int n = blockIdx.x * 4 + wave;
    int sub = lane >> 5, cl = lane & 31;
    int c = cl * 8, h = cl >> 4;
    int beg = row_start[n], end = row_start[n + 1];
    if (beg == end) {       // isolated node: h' = Wh
        if (sub == 0) {
            bf16x8 wh = *(const bf16x8*)(Wh + (size_t)n*F + c);
            f32x4 o0, o1;
            #pragma unroll
            for (int i = 0; i < 4; ++i) { o0[i] = (float)wh[i]; o1[i] = (float)wh[4+i]; }
            *(f32x4*)(out + (size_t)n*F + c)     = o0;
            *(f32x4*)(out + (size_t)n*F + c + 4) = o1;
        }
        return;
    }
    float2 sv = ((const float2*)s_arr)[n];
    float sum0 = 0.f, sum1 = 0.f;
    float a[8] = {0,0,0,0,0,0,0,0};
    float bacc[8] = {0,0,0,0,0,0,0,0};
    const float* sph = h ? sp1[wave] : sp0[wave];

    for (int c0 = beg; c0 < end; c0 += CAP) {
        int cnt = min(CAP, end - c0);
        // Phase A: fill p/d chunk (wave-local)
        for (int j = lane; j < cnt; j += 64) {
            int d = sdst[c0 + j];
            float2 tv = ((const float2*)t_arr)[d];
            float e0 = sv.x + tv.x; e0 = (e0 >= 0.f) ? e0 : 0.2f * e0;
            float e1 = sv.y + tv.y; e1 = (e1 >= 0.f) ? e1 : 0.2f * e1;
            float p0 = __expf(e0), p1 = __expf(e1);
            sp0[wave][j] = p0;
            sp1[wave][j] = p1;
            sd[wave][j]  = d;
            sum0 += p0;
            sum1 += p1;
        }
        // Phase B: gather + FMA (8 edges/iter, 4 per sub-slot)
        int j = 0;
        for (; j + 8 <= cnt; j += 8) {
            int j0 = j + sub, j1 = j + 2 + sub, j2 = j + 4 + sub, j3 = j + 6 + sub;
            int d0 = sd[wave][j0], d1 = sd[wave][j1];
            int d2 = sd[wave][j2], d3 = sd[wave][j3];
            float p0 = sph[j0], p1 = sph[j1], p2 = sph[j2], p3 = sph[j3];
            bf16x8 w0 = *(const bf16x8*)(Wh + (size_t)d0*F + c);
            bf16x8 w1 = *(const bf16x8*)(Wh + (size_t)d1*F + c);
            bf16x8 w2 = *(const bf16x8*)(Wh + (size_t)d2*F + c);
            bf16x8 w3 = *(const bf16x8*)(Wh + (size_t)d3*F + c);
            #pragma unroll
            for (int i = 0; i < 8; ++i) {
                a[i]    += p0 * (float)w0[i];
                bacc[i] += p1 * (float)w1[i];
                a[i]    += p2 * (float)w2[i];
                bacc[i] += p3 * (float)w3[i];
            }
        }
        for (; j < cnt; j += 2) {
            int jj = j + sub;
            int jc = (jj < cnt) ? jj : 0;
            float p = (jj < cnt) ? sph[jc] : 0.f;
            int d = sd[wave][jc];
            bf16x8 w = *(const bf16x8*)(Wh + (size_t)d*F + c);
            #pragma unroll
            for (int i = 0; i < 8; ++i) a[i] += p * (float)w[i];
        }
    }
    #pragma unroll
    for (int m = 32; m >= 1; m >>= 1) {
        sum0 += __shfl_xor(sum0, m);
        sum1 += __shfl_xor(sum1, m);
    }
    float inv = 1.f / (h ? sum1 : sum0);
    #pragma unroll
    for (int i = 0; i < 8; ++i) {
        a[i] += bacc[i];
        a[i] += __shfl_xor(a[i], 32);      // merge odd-slot partial
    }
    if (sub == 0) {
        f32x4 o0, o1;
        #pragma unroll
        for (int i = 0; i < 4; ++i) { o0[i] = a[i] * inv; o1[i] = a[4+i] * inv; }
        *(f32x4*)(out + (size_t)n*F + c)     = o0;
        *(f32x4*)(out + (size_t)n*F + c + 4) = o1;
    }
}

// ---------------- launch ----------------
extern "C" void kernel_launch(void* const* d_in, const int* in_sizes, int n_in,
                              void* d_out, int out_size, void* d_ws, size_t ws_size,
                              hipStream_t stream) {
    const float* x  = (const float*)d_in[0];
    const int*   ei = (const int*)d_in[1];
    const float* Ww = (const float*)d_in[2];
    const float* Wb = (const float*)d_in[3];
    const float* a  = (const float*)d_in[4];
    float* out = (float*)d_out;
    const int* src = ei;              // edge_index[0]
    const int* dst = ei + N_EDGES;    // edge_index[1]

    // workspace layout (~32 MB), 16B-aligned slices
    char* ws = (char*)d_ws;
    bf16*  Wh        = (bf16*)ws;   ws += (size_t)N_NODES * F * 2;       // 25.6 MB
    bf16*  Wt        = (bf16*)ws;   ws += (size_t)IN_DIM * F * 2;        // 128 KB
    float* s_arr     = (float*)ws;  ws += (size_t)N_NODES * 2 * 4;
    float* t_arr     = (float*)ws;  ws += (size_t)N_NODES * 2 * 4;
    int*   excl      = (int*)ws;    ws += (size_t)N_NODES * 4;
    int*   bsum      = (int*)ws;    ws += 64 * 4;
    int*   row_start = (int*)ws;    ws += (size_t)(N_NODES + 1) * 4 + 12; // pad to 16B
    unsigned short* prefix8 = (unsigned short*)ws; ws += (size_t)N_NODES * 8 * 2; // 800 KB
    unsigned char*  rank    = (unsigned char*)ws;  ws += (size_t)N_EDGES + 16;    // 800 KB
    int*   xcdtab    = (int*)ws;    ws += (size_t)NBLK_H * 4 + 12;       // pad to 16B
    int*   sdst      = (int*)ws;    ws += (size_t)N_EDGES * 4;           // 3.2 MB

    // deg8 (8 x N_NODES = 1.6 MB) ALIASES sdst: deg copies are consumed by
    // k_scan_local (dispatch 4) strictly before k_scatter writes sdst (disp 6).
    int* deg8 = sdst;

    k_transpose<<<IN_DIM, F, 0, stream>>>(Ww, Wt, deg8);
    k_hist<<<NBLK_H, 256, 0, stream>>>(src, deg8, rank, xcdtab);
    k_gemm<<<(N_NODES + 63) / 64, 256, 0, stream>>>(x, Wt, Wb, a, Wh, s_arr, t_arr);
    k_scan_local<<<N_SB, SCAN_B, 0, stream>>>(deg8, excl, bsum, prefix8);
    k_scan_final<<<(N_NODES + 255) / 256, 256, 0, stream>>>(excl, bsum, row_start);
    k_scatter<<<NBLK_H, 256, 0, stream>>>(src, dst, rank, prefix8,
                                          row_start, xcdtab, sdst);
    k_agg<<<N_NODES / 4, 256, 0, stream>>>(Wh, s_arr, t_arr, row_start, sdst, out);
}

// Round 6
// 250.019 us; speedup vs baseline: 1.0147x; 1.0147x over previous
//
#include <hip/hip_runtime.h>
#include <hip/hip_bf16.h>
#include <math.h>

#define N_NODES 50000
#define IN_DIM 256
#define OUT_DIM 128
#define NUM_HEADS 2
#define N_EDGES 800000
#define F (OUT_DIM*NUM_HEADS)   /* 256 */
#define SCAN_B 1024
#define N_SB ((N_NODES + SCAN_B - 1) / SCAN_B)   /* 49 */
#define LDSP 264                 /* 256 + 8 pad: 132-word row stride = 4 mod 32 banks */
#define CAP 128                  /* per-wave LDS edge chunk in k_agg */
#define N_COPIES 8               /* XCD-private histogram copies */
#define NBLK_H (N_EDGES / 256)   /* 3125 hist/scatter blocks, exactly 1 edge/thread */

typedef __bf16 bf16;
typedef __bf16 bf16x8 __attribute__((ext_vector_type(8)));
typedef float  f32x4  __attribute__((ext_vector_type(4)));
typedef unsigned short u16x8 __attribute__((ext_vector_type(8)));

// ---------------- K0: W -> Wt (bf16, transposed) + zero deg copies -------
__global__ void k_transpose(const float* __restrict__ W, bf16* __restrict__ Wt,
                            int* __restrict__ deg8) {
    int k = blockIdx.x;      // 0..IN_DIM-1
    int n = threadIdx.x;     // 0..F-1
    Wt[(size_t)n*IN_DIM + k] = (bf16)W[(size_t)k*F + n];
    int id = blockIdx.x * F + threadIdx.x;
    for (int i = id; i < N_COPIES * N_NODES; i += IN_DIM * F)
        deg8[i] = 0;
}

// ---------------- K1: standalone degree histogram + rank recording ------
__global__ __launch_bounds__(256) void k_hist(const int* __restrict__ src,
                                              int* __restrict__ deg8,
                                              unsigned char* __restrict__ rank,
                                              int* __restrict__ xcdtab) {
    unsigned xcc;
    asm volatile("s_getreg_b32 %0, hwreg(HW_REG_XCC_ID, 0, 4)" : "=s"(xcc));
    xcc &= (N_COPIES - 1);
    if (threadIdx.x == 0) xcdtab[blockIdx.x] = (int)xcc;
    int e = blockIdx.x * 256 + threadIdx.x;      // grid covers N_EDGES exactly
    int s = src[e];
    int r = __hip_atomic_fetch_add(&deg8[(size_t)xcc * N_NODES + s], 1,
                                   __ATOMIC_RELAXED, __HIP_MEMORY_SCOPE_WORKGROUP);
    rank[e] = (unsigned char)r;
}

// ---------------- K2: Wh = x @ W + b, fused s,t  (MFMA bf16) -------------
// Round-6 restructure: the old K-loop exposed ~250cyc of L2 latency per
// K-step (92 VGPRs forced serial Wt-load->mfma). Now: issue ALL 16 X
// staging loads + ALL 32 Wt B-frag gathers back-to-back (48 loads, one
// memory round-trip), hold B-frags in registers across the barrier
// (launch_bounds(256,2) -> 256-VGPR cap), then run the MFMA loop with
// LDS-only reads. Epilogue unchanged.
__global__ __launch_bounds__(256, 2) void k_gemm(const float* __restrict__ X,
                                              const bf16* __restrict__ Wt,
                                              const float* __restrict__ Wb,
                                              const float* __restrict__ Av,
                                              bf16* __restrict__ Wh,
                                              float* __restrict__ s_arr,
                                              float* __restrict__ t_arr) {
    __shared__ bf16 As[64 * LDSP];
    __shared__ float sS[2][64], sT[2][64];
    int t = threadIdx.x;
    int wave = t >> 6, lane = t & 63;
    int quad = lane >> 4, l16 = lane & 15;
    int row0 = blockIdx.x * 64;
    int col0 = wave * 64;
    int h = wave >> 1;

    // phase 1a: issue X staging loads (16 dwordx4 per thread, independent)
    int rr = t >> 5;
    int cc = (t & 31) * 8;
    f32x4 slo[8], shi[8];
    #pragma unroll
    for (int i = 0; i < 8; ++i) {
        int r = row0 + 8*i + rr;
        r = (r < N_NODES) ? r : (N_NODES - 1);
        const float* p = X + (size_t)r * IN_DIM + cc;
        slo[i] = *(const f32x4*)p;
        shi[i] = *(const f32x4*)(p + 4);
    }

    // phase 1b: issue all 32 B-frag gathers (independent, live across barrier)
    bf16x8 bfrag[4][8];
    #pragma unroll
    for (int ni = 0; ni < 4; ++ni)
        #pragma unroll
        for (int ks = 0; ks < 8; ++ks)
            bfrag[ni][ks] = *(const bf16x8*)(Wt + (size_t)(col0 + ni*16 + l16)*IN_DIM
                                                + ks*32 + quad*8);

    // phase 1c: convert + write staging tile to LDS (waits only on X loads)
    #pragma unroll
    for (int i = 0; i < 8; ++i) {
        bf16x8 pk;
        #pragma unroll
        for (int q = 0; q < 4; ++q) {
            pk[q]   = (bf16)slo[i][q];
            pk[q+4] = (bf16)shi[i][q];
        }
        *(bf16x8*)(As + (8*i + rr) * LDSP + cc) = pk;
    }
    if (t < 128) { sS[t >> 6][t & 63] = 0.f; sT[t >> 6][t & 63] = 0.f; }
    __syncthreads();

    // phase 2: MFMA loop, LDS reads only (B already in registers)
    f32x4 acc[4][4] = {};
    #pragma unroll
    for (int ks = 0; ks < 8; ++ks) {
        int kb = ks * 32;
        bf16x8 afrag[4];
        #pragma unroll
        for (int mi = 0; mi < 4; ++mi)
            afrag[mi] = *(const bf16x8*)(As + (mi*16 + l16)*LDSP + kb + quad*8);

        #pragma unroll
        for (int mi = 0; mi < 4; ++mi)
            #pragma unroll
            for (int ni = 0; ni < 4; ++ni)
                acc[mi][ni] = __builtin_amdgcn_mfma_f32_16x16x32_bf16(
                                  afrag[mi], bfrag[ni][ks], acc[mi][ni], 0, 0, 0);
    }

    float bias_l[4], as_l[4], at_l[4];
    #pragma unroll
    for (int ni = 0; ni < 4; ++ni) {
        int c = col0 + ni*16 + l16;
        int d = c & (OUT_DIM - 1);
        bias_l[ni] = Wb[c];
        as_l[ni]   = Av[d];
        at_l[ni]   = Av[OUT_DIM + d];
    }

    // s,t partials from accumulators (C layout: col=lane&15, row=quad*4+reg)
    #pragma unroll
    for (int mi = 0; mi < 4; ++mi) {
        #pragma unroll
        for (int reg = 0; reg < 4; ++reg) {
            int rl = mi*16 + quad*4 + reg;
            float ps = 0.f, pt = 0.f;
            #pragma unroll
            for (int ni = 0; ni < 4; ++ni) {
                float val = acc[mi][ni][reg] + bias_l[ni];
                ps += val * as_l[ni];
                pt += val * at_l[ni];
            }
            #pragma unroll
            for (int m = 8; m >= 1; m >>= 1) {
                ps += __shfl_xor(ps, m);
                pt += __shfl_xor(pt, m);
            }
            if ((lane & 15) == 0) {
                atomicAdd(&sS[h][rl], ps);
                atomicAdd(&sT[h][rl], pt);
            }
        }
    }

    // repack acc -> As (bias added) for coalesced Wh stores
    __syncthreads();          // all waves done with As compute reads
    #pragma unroll
    for (int mi = 0; mi < 4; ++mi)
        #pragma unroll
        for (int ni = 0; ni < 4; ++ni) {
            int ccc = col0 + ni*16 + l16;
            #pragma unroll
            for (int reg = 0; reg < 4; ++reg) {
                int rl = mi*16 + quad*4 + reg;
                As[rl*LDSP + ccc] = (bf16)(acc[mi][ni][reg] + bias_l[ni]);
            }
        }
    __syncthreads();

    // coalesced write-out: 8 rounds x (ds_read_b128 + global_store_dwordx4)
    #pragma unroll
    for (int i = 0; i < 8; ++i) {
        int idx = i * 2048 + t * 8;     // 2048 elems (=8 rows) per round
        int row = idx >> 8;
        int ccw = idx & 255;
        bf16x8 v = *(const bf16x8*)(As + row*LDSP + ccw);
        int grow = row0 + row;
        if (grow < N_NODES)
            *(bf16x8*)(Wh + (size_t)grow*F + ccw) = v;
    }

    if (t < 128) {
        int hh = t >> 6, rl = t & 63;
        int n = row0 + rl;
        if (n < N_NODES) {
            s_arr[n*2 + hh] = sS[hh][rl];
            t_arr[n*2 + hh] = sT[hh][rl];
        }
    }
}

// ---------------- K4a: per-block exclusive scan (folds 8 deg copies) -----
__global__ __launch_bounds__(SCAN_B) void k_scan_local(const int* __restrict__ deg8,
                                                       int* __restrict__ excl,
                                                       int* __restrict__ bsum,
                                                       unsigned short* __restrict__ prefix8) {
    __shared__ int lds[SCAN_B];
    int t = threadIdx.x;
    int i = blockIdx.x * SCAN_B + t;
    int v = 0;
    if (i < N_NODES) {
        u16x8 pf;
        int run = 0;
        #pragma unroll
        for (int c = 0; c < N_COPIES; ++c) {
            pf[c] = (unsigned short)run;
            run += deg8[(size_t)c * N_NODES + i];
        }
        v = run;
        *(u16x8*)(prefix8 + (size_t)i * 8) = pf;
    }
    lds[t] = v;
    __syncthreads();
    for (int off = 1; off < SCAN_B; off <<= 1) {
        int u = (t >= off) ? lds[t - off] : 0;
        __syncthreads();
        lds[t] += u;
        __syncthreads();
    }
    if (i < N_NODES) excl[i] = lds[t] - v;          // exclusive-local
    if (t == SCAN_B - 1) bsum[blockIdx.x] = lds[t]; // block total
}

// ---------------- K4b: finalize exclusive scan (folds block-sum scan) ----
__global__ __launch_bounds__(256) void k_scan_final(const int* __restrict__ excl,
                                                    const int* __restrict__ bsum,
                                                    int* __restrict__ row_start) {
    __shared__ int sboff[64];
    int t = threadIdx.x;
    if (t < 64) {
        int orig = (t < N_SB) ? bsum[t] : 0;
        int v = orig;
        #pragma unroll
        for (int off = 1; off < 64; off <<= 1) {
            int u = __shfl_up(v, off);
            if (t >= off) v += u;
        }
        sboff[t] = v - orig;
        if (t == 63 && blockIdx.x == 0) row_start[N_NODES] = v;
    }
    __syncthreads();
    int i = blockIdx.x * 256 + t;
    if (i < N_NODES)
        row_start[i] = excl[i] + sboff[i >> 10];
}

// ---------------- K5: ATOMIC-FREE scatter into CSR slots -----------------
__global__ __launch_bounds__(256) void k_scatter(const int* __restrict__ src,
                                                 const int* __restrict__ dst,
                                                 const unsigned char* __restrict__ rank,
                                                 const unsigned short* __restrict__ prefix8,
                                                 const int* __restrict__ row_start,
                                                 const int* __restrict__ xcdtab,
                                                 int* __restrict__ sorted_dst) {
    int e = blockIdx.x * 256 + threadIdx.x;      // grid covers N_EDGES exactly
    int c = xcdtab[blockIdx.x];                  // block-uniform scalar load
    int s = src[e];
    int pos = row_start[s] + (int)prefix8[(size_t)s * 8 + c] + (int)rank[e];
    sorted_dst[pos] = dst[e];
}

// ---------------- K6: fused softmax + gather+FMA aggregation -------------
__global__ __launch_bounds__(256) void k_agg(const bf16* __restrict__ Wh,
                                             const float* __restrict__ s_arr,
                                             const float* __restrict__ t_arr,
                                             const int* __restrict__ row_start,
                                             const int* __restrict__ sdst,
                                             float* __restrict__ out) {
    __shared__ float sp0[4][CAP];
    __shared__ float sp1[4][CAP];
    __shared__ int   sd[4][CAP];
    int wave = threadIdx.x >> 6, lane = threadIdx.x & 63;
    int n = blockIdx.x * 4 + wave;
    int sub = lane >> 5, cl = lane & 31;
    int c = cl * 8, h = cl >> 4;
    int beg = row_start[n], end = row_start[n + 1];
    if (beg == end) {       // isolated node: h' = Wh
        if (sub == 0) {
            bf16x8 wh = *(const bf16x8*)(Wh + (size_t)n*F + c);
            f32x4 o0, o1;
            #pragma unroll
            for (int i = 0; i < 4; ++i) { o0[i] = (float)wh[i]; o1[i] = (float)wh[4+i]; }
            *(f32x4*)(out + (size_t)n*F + c)     = o0;
            *(f32x4*)(out + (size_t)n*F + c + 4) = o1;
        }
        return;
    }
    float2 sv = ((const float2*)s_arr)[n];
    float sum0 = 0.f, sum1 = 0.f;
    float a[8] = {0,0,0,0,0,0,0,0};
    float bacc[8] = {0,0,0,0,0,0,0,0};
    const float* sph = h ? sp1[wave] : sp0[wave];

    for (int c0 = beg; c0 < end; c0 += CAP) {
        int cnt = min(CAP, end - c0);
        // Phase A: fill p/d chunk (wave-local)
        for (int j = lane; j < cnt; j += 64) {
            int d = sdst[c0 + j];
            float2 tv = ((const float2*)t_arr)[d];
            float e0 = sv.x + tv.x; e0 = (e0 >= 0.f) ? e0 : 0.2f * e0;
            float e1 = sv.y + tv.y; e1 = (e1 >= 0.f) ? e1 : 0.2f * e1;
            float p0 = __expf(e0), p1 = __expf(e1);
            sp0[wave][j] = p0;
            sp1[wave][j] = p1;
            sd[wave][j]  = d;
            sum0 += p0;
            sum1 += p1;
        }
        // Phase B: gather + FMA (8 edges/iter, 4 per sub-slot)
        int j = 0;
        for (; j + 8 <= cnt; j += 8) {
            int j0 = j + sub, j1 = j + 2 + sub, j2 = j + 4 + sub, j3 = j + 6 + sub;
            int d0 = sd[wave][j0], d1 = sd[wave][j1];
            int d2 = sd[wave][j2], d3 = sd[wave][j3];
            float p0 = sph[j0], p1 = sph[j1], p2 = sph[j2], p3 = sph[j3];
            bf16x8 w0 = *(const bf16x8*)(Wh + (size_t)d0*F + c);
            bf16x8 w1 = *(const bf16x8*)(Wh + (size_t)d1*F + c);
            bf16x8 w2 = *(const bf16x8*)(Wh + (size_t)d2*F + c);
            bf16x8 w3 = *(const bf16x8*)(Wh + (size_t)d3*F + c);
            #pragma unroll
            for (int i = 0; i < 8; ++i) {
                a[i]    += p0 * (float)w0[i];
                bacc[i] += p1 * (float)w1[i];
                a[i]    += p2 * (float)w2[i];
                bacc[i] += p3 * (float)w3[i];
            }
        }
        for (; j < cnt; j += 2) {
            int jj = j + sub;
            int jc = (jj < cnt) ? jj : 0;
            float p = (jj < cnt) ? sph[jc] : 0.f;
            int d = sd[wave][jc];
            bf16x8 w = *(const bf16x8*)(Wh + (size_t)d*F + c);
            #pragma unroll
            for (int i = 0; i < 8; ++i) a[i] += p * (float)w[i];
        }
    }
    #pragma unroll
    for (int m = 32; m >= 1; m >>= 1) {
        sum0 += __shfl_xor(sum0, m);
        sum1 += __shfl_xor(sum1, m);
    }
    float inv = 1.f / (h ? sum1 : sum0);
    #pragma unroll
    for (int i = 0; i < 8; ++i) {
        a[i] += bacc[i];
        a[i] += __shfl_xor(a[i], 32);      // merge odd-slot partial
    }
    if (sub == 0) {
        f32x4 o0, o1;
        #pragma unroll
        for (int i = 0; i < 4; ++i) { o0[i] = a[i] * inv; o1[i] = a[4+i] * inv; }
        *(f32x4*)(out + (size_t)n*F + c)     = o0;
        *(f32x4*)(out + (size_t)n*F + c + 4) = o1;
    }
}

// ---------------- launch ----------------
extern "C" void kernel_launch(void* const* d_in, const int* in_sizes, int n_in,
                              void* d_out, int out_size, void* d_ws, size_t ws_size,
                              hipStream_t stream) {
    const float* x  = (const float*)d_in[0];
    const int*   ei = (const int*)d_in[1];
    const float* Ww = (const float*)d_in[2];
    const float* Wb = (const float*)d_in[3];
    const float* a  = (const float*)d_in[4];
    float* out = (float*)d_out;
    const int* src = ei;              // edge_index[0]
    const int* dst = ei + N_EDGES;    // edge_index[1]

    // workspace layout (~32 MB), 16B-aligned slices
    char* ws = (char*)d_ws;
    bf16*  Wh        = (bf16*)ws;   ws += (size_t)N_NODES * F * 2;       // 25.6 MB
    bf16*  Wt        = (bf16*)ws;   ws += (size_t)IN_DIM * F * 2;        // 128 KB
    float* s_arr     = (float*)ws;  ws += (size_t)N_NODES * 2 * 4;
    float* t_arr     = (float*)ws;  ws += (size_t)N_NODES * 2 * 4;
    int*   excl      = (int*)ws;    ws += (size_t)N_NODES * 4;
    int*   bsum      = (int*)ws;    ws += 64 * 4;
    int*   row_start = (int*)ws;    ws += (size_t)(N_NODES + 1) * 4 + 12; // pad to 16B
    unsigned short* prefix8 = (unsigned short*)ws; ws += (size_t)N_NODES * 8 * 2; // 800 KB
    unsigned char*  rank    = (unsigned char*)ws;  ws += (size_t)N_EDGES + 16;    // 800 KB
    int*   xcdtab    = (int*)ws;    ws += (size_t)NBLK_H * 4 + 12;       // pad to 16B
    int*   sdst      = (int*)ws;    ws += (size_t)N_EDGES * 4;           // 3.2 MB

    // deg8 (8 x N_NODES = 1.6 MB) ALIASES sdst: deg copies are consumed by
    // k_scan_local (dispatch 4) strictly before k_scatter writes sdst (disp 6).
    int* deg8 = sdst;

    k_transpose<<<IN_DIM, F, 0, stream>>>(Ww, Wt, deg8);
    k_hist<<<NBLK_H, 256, 0, stream>>>(src, deg8, rank, xcdtab);
    k_gemm<<<(N_NODES + 63) / 64, 256, 0, stream>>>(x, Wt, Wb, a, Wh, s_arr, t_arr);
    k_scan_local<<<N_SB, SCAN_B, 0, stream>>>(deg8, excl, bsum, prefix8);
    k_scan_final<<<(N_NODES + 255) / 256, 256, 0, stream>>>(excl, bsum, row_start);
    k_scatter<<<NBLK_H, 256, 0, stream>>>(src, dst, rank, prefix8,
                                          row_start, xcdtab, sdst);
    k_agg<<<N_NODES / 4, 256, 0, stream>>>(Wh, s_arr, t_arr, row_start, sdst, out);
}

// Round 7
// 224.297 us; speedup vs baseline: 1.1311x; 1.1147x over previous
//
#include <hip/hip_runtime.h>
#include <hip/hip_bf16.h>
#include <math.h>

#define N_NODES 50000
#define IN_DIM 256
#define OUT_DIM 128
#define NUM_HEADS 2
#define N_EDGES 800000
#define F (OUT_DIM*NUM_HEADS)   /* 256 */
#define SCAN_B 1024
#define N_SB ((N_NODES + SCAN_B - 1) / SCAN_B)   /* 49 */
#define LDSP 264                 /* 256 + 8 pad: 132-word row stride = 4 mod 32 banks */
#define CAP 128                  /* per-wave LDS edge chunk in k_agg */
#define N_COPIES 8               /* XCD-private histogram copies */
#define NBLK_G ((N_NODES + 63) / 64)   /* 782 gemm tiles */
#define NBLK_H (N_EDGES / 256)   /* 3125 hist/scatter chunks, 1 edge/thread */
#define NBLK_FUSED 3910          /* 782*5: r==4 -> gemm (782), else hist (3128) */

typedef __bf16 bf16;
typedef __bf16 bf16x8 __attribute__((ext_vector_type(8)));
typedef float  f32x4  __attribute__((ext_vector_type(4)));
typedef unsigned short u16x8 __attribute__((ext_vector_type(8)));

// ---------------- K0: W -> Wt (bf16, transposed) + zero deg copies -------
__global__ void k_transpose(const float* __restrict__ W, bf16* __restrict__ Wt,
                            int* __restrict__ deg8) {
    int k = blockIdx.x;      // 0..IN_DIM-1
    int n = threadIdx.x;     // 0..F-1
    Wt[(size_t)n*IN_DIM + k] = (bf16)W[(size_t)k*F + n];
    int id = blockIdx.x * F + threadIdx.x;
    for (int i = id; i < N_COPIES * N_NODES; i += IN_DIM * F)
        deg8[i] = 0;
}

// ---------------- K1: FUSED gemm | hist (block-range split, 1:4) ---------
// blockIdx%5==4 -> gemm tile q=blockIdx/5 (782 tiles); else hist chunk
// hi=q*4+r (3128 slots, 3125 used). Both kinds run CONCURRENTLY across the
// dispatch: hist's L2-local atomics hide under gemm's MFMA/memory phase
// (and vice versa). Unlike the round-0..3 fusion, hist blocks have no
// barrier (no vmcnt drain vs staging) and gemm blocks have no atomics.
__global__ __launch_bounds__(256, 2) void k_gemm_hist(
                                              const float* __restrict__ X,
                                              const bf16* __restrict__ Wt,
                                              const float* __restrict__ Wb,
                                              const float* __restrict__ Av,
                                              const int* __restrict__ src,
                                              int* __restrict__ deg8,
                                              unsigned char* __restrict__ rank,
                                              int* __restrict__ xcdtab,
                                              bf16* __restrict__ Wh,
                                              float* __restrict__ s_arr,
                                              float* __restrict__ t_arr) {
    __shared__ bf16 As[64 * LDSP];
    __shared__ float sS[2][64], sT[2][64];
    int b = blockIdx.x;
    int q = b / 5, r5 = b % 5;
    int t = threadIdx.x;

    if (r5 != 4) {
        // ---------------- hist branch ----------------
        int hi = q * 4 + r5;
        if (hi >= NBLK_H) return;
        unsigned xcc;
        asm volatile("s_getreg_b32 %0, hwreg(HW_REG_XCC_ID, 0, 4)" : "=s"(xcc));
        xcc &= (N_COPIES - 1);
        if (t == 0) xcdtab[hi] = (int)xcc;
        int e = hi * 256 + t;                    // covers N_EDGES exactly
        int s = src[e];
        int rr = __hip_atomic_fetch_add(&deg8[(size_t)xcc * N_NODES + s], 1,
                                        __ATOMIC_RELAXED, __HIP_MEMORY_SCOPE_WORKGROUP);
        rank[e] = (unsigned char)rr;
        return;
    }

    // ---------------- gemm branch (round-6 body, tile index q) ----------
    int wave = t >> 6, lane = t & 63;
    int quad = lane >> 4, l16 = lane & 15;
    int row0 = q * 64;
    int col0 = wave * 64;
    int h = wave >> 1;

    // phase 1a: issue X staging loads (16 dwordx4 per thread, independent)
    int rr = t >> 5;
    int cc = (t & 31) * 8;
    f32x4 slo[8], shi[8];
    #pragma unroll
    for (int i = 0; i < 8; ++i) {
        int r = row0 + 8*i + rr;
        r = (r < N_NODES) ? r : (N_NODES - 1);
        const float* p = X + (size_t)r * IN_DIM + cc;
        slo[i] = *(const f32x4*)p;
        shi[i] = *(const f32x4*)(p + 4);
    }

    // phase 1b: issue all 32 B-frag gathers (independent, live across barrier)
    bf16x8 bfrag[4][8];
    #pragma unroll
    for (int ni = 0; ni < 4; ++ni)
        #pragma unroll
        for (int ks = 0; ks < 8; ++ks)
            bfrag[ni][ks] = *(const bf16x8*)(Wt + (size_t)(col0 + ni*16 + l16)*IN_DIM
                                                + ks*32 + quad*8);

    // phase 1c: convert + write staging tile to LDS (waits only on X loads)
    #pragma unroll
    for (int i = 0; i < 8; ++i) {
        bf16x8 pk;
        #pragma unroll
        for (int qq = 0; qq < 4; ++qq) {
            pk[qq]   = (bf16)slo[i][qq];
            pk[qq+4] = (bf16)shi[i][qq];
        }
        *(bf16x8*)(As + (8*i + rr) * LDSP + cc) = pk;
    }
    if (t < 128) { sS[t >> 6][t & 63] = 0.f; sT[t >> 6][t & 63] = 0.f; }
    __syncthreads();

    // phase 2: MFMA loop, LDS reads only (B already in registers)
    f32x4 acc[4][4] = {};
    #pragma unroll
    for (int ks = 0; ks < 8; ++ks) {
        int kb = ks * 32;
        bf16x8 afrag[4];
        #pragma unroll
        for (int mi = 0; mi < 4; ++mi)
            afrag[mi] = *(const bf16x8*)(As + (mi*16 + l16)*LDSP + kb + quad*8);

        #pragma unroll
        for (int mi = 0; mi < 4; ++mi)
            #pragma unroll
            for (int ni = 0; ni < 4; ++ni)
                acc[mi][ni] = __builtin_amdgcn_mfma_f32_16x16x32_bf16(
                                  afrag[mi], bfrag[ni][ks], acc[mi][ni], 0, 0, 0);
    }

    float bias_l[4], as_l[4], at_l[4];
    #pragma unroll
    for (int ni = 0; ni < 4; ++ni) {
        int c = col0 + ni*16 + l16;
        int d = c & (OUT_DIM - 1);
        bias_l[ni] = Wb[c];
        as_l[ni]   = Av[d];
        at_l[ni]   = Av[OUT_DIM + d];
    }

    // s,t partials from accumulators (C layout: col=lane&15, row=quad*4+reg)
    #pragma unroll
    for (int mi = 0; mi < 4; ++mi) {
        #pragma unroll
        for (int reg = 0; reg < 4; ++reg) {
            int rl = mi*16 + quad*4 + reg;
            float ps = 0.f, pt = 0.f;
            #pragma unroll
            for (int ni = 0; ni < 4; ++ni) {
                float val = acc[mi][ni][reg] + bias_l[ni];
                ps += val * as_l[ni];
                pt += val * at_l[ni];
            }
            #pragma unroll
            for (int m = 8; m >= 1; m >>= 1) {
                ps += __shfl_xor(ps, m);
                pt += __shfl_xor(pt, m);
            }
            if ((lane & 15) == 0) {
                atomicAdd(&sS[h][rl], ps);
                atomicAdd(&sT[h][rl], pt);
            }
        }
    }

    // repack acc -> As (bias added) for coalesced Wh stores
    __syncthreads();          // all waves done with As compute reads
    #pragma unroll
    for (int mi = 0; mi < 4; ++mi)
        #pragma unroll
        for (int ni = 0; ni < 4; ++ni) {
            int ccc = col0 + ni*16 + l16;
            #pragma unroll
            for (int reg = 0; reg < 4; ++reg) {
                int rl = mi*16 + quad*4 + reg;
                As[rl*LDSP + ccc] = (bf16)(acc[mi][ni][reg] + bias_l[ni]);
            }
        }
    __syncthreads();

    // coalesced write-out: 8 rounds x (ds_read_b128 + global_store_dwordx4)
    #pragma unroll
    for (int i = 0; i < 8; ++i) {
        int idx = i * 2048 + t * 8;     // 2048 elems (=8 rows) per round
        int row = idx >> 8;
        int ccw = idx & 255;
        bf16x8 v = *(const bf16x8*)(As + row*LDSP + ccw);
        int grow = row0 + row;
        if (grow < N_NODES)
            *(bf16x8*)(Wh + (size_t)grow*F + ccw) = v;
    }

    if (t < 128) {
        int hh = t >> 6, rl = t & 63;
        int n = row0 + rl;
        if (n < N_NODES) {
            s_arr[n*2 + hh] = sS[hh][rl];
            t_arr[n*2 + hh] = sT[hh][rl];
        }
    }
}

// ---------------- K2: per-block exclusive scan (folds 8 deg copies) ------
// Emits excl (block-local exclusive), bsum (block totals), prefix8.
// Global row_start is reconstructed inline by k_scatter/k_agg.
__global__ __launch_bounds__(SCAN_B) void k_scan_local(const int* __restrict__ deg8,
                                                       int* __restrict__ excl,
                                                       int* __restrict__ bsum,
                                                       unsigned short* __restrict__ prefix8) {
    __shared__ int lds[SCAN_B];
    int t = threadIdx.x;
    int i = blockIdx.x * SCAN_B + t;
    int v = 0;
    if (i < N_NODES) {
        u16x8 pf;
        int run = 0;
        #pragma unroll
        for (int c = 0; c < N_COPIES; ++c) {
            pf[c] = (unsigned short)run;
            run += deg8[(size_t)c * N_NODES + i];
        }
        v = run;
        *(u16x8*)(prefix8 + (size_t)i * 8) = pf;
    }
    lds[t] = v;
    __syncthreads();
    for (int off = 1; off < SCAN_B; off <<= 1) {
        int u = (t >= off) ? lds[t - off] : 0;
        __syncthreads();
        lds[t] += u;
        __syncthreads();
    }
    if (i < N_NODES) excl[i] = lds[t] - v;          // exclusive-local
    if (t == SCAN_B - 1) bsum[blockIdx.x] = lds[t]; // block total
}

// ---------------- K3: ATOMIC-FREE scatter (inline block-sum scan) --------
// pos = excl[s] + sboff[s>>10] + prefix8[s][c] + rank[e]. sboff (exclusive
// scan of the 49 block sums) recomputed per block: 49 loads + 64-lane scan.
__global__ __launch_bounds__(256) void k_scatter(const int* __restrict__ src,
                                                 const int* __restrict__ dst,
                                                 const unsigned char* __restrict__ rank,
                                                 const unsigned short* __restrict__ prefix8,
                                                 const int* __restrict__ excl,
                                                 const int* __restrict__ bsum,
                                                 const int* __restrict__ xcdtab,
                                                 int* __restrict__ sorted_dst) {
    __shared__ int sboff[64];
    int t = threadIdx.x;
    if (t < 64) {
        int orig = (t < N_SB) ? bsum[t] : 0;
        int v = orig;
        #pragma unroll
        for (int off = 1; off < 64; off <<= 1) {
            int u = __shfl_up(v, off);
            if (t >= off) v += u;
        }
        sboff[t] = v - orig;
    }
    __syncthreads();
    int e = blockIdx.x * 256 + t;                // grid covers N_EDGES exactly
    int c = xcdtab[blockIdx.x];                  // block-uniform scalar load
    int s = src[e];
    int pos = excl[s] + sboff[s >> 10] + (int)prefix8[(size_t)s * 8 + c] + (int)rank[e];
    sorted_dst[pos] = dst[e];
}

// ---------------- K4: fused softmax + gather+FMA aggregation -------------
// wave per node; row_start reconstructed inline (excl + block-sum scan).
__global__ __launch_bounds__(256) void k_agg(const bf16* __restrict__ Wh,
                                             const float* __restrict__ s_arr,
                                             const float* __restrict__ t_arr,
                                             const int* __restrict__ excl,
                                             const int* __restrict__ bsum,
                                             const int* __restrict__ sdst,
                                             float* __restrict__ out) {
    __shared__ float sp0[4][CAP];
    __shared__ float sp1[4][CAP];
    __shared__ int   sd[4][CAP];
    __shared__ int   sboff[64];
    int t = threadIdx.x;
    if (t < 64) {
        int orig = (t < N_SB) ? bsum[t] : 0;
        int v = orig;
        #pragma unroll
        for (int off = 1; off < 64; off <<= 1) {
            int u = __shfl_up(v, off);
            if (t >= off) v += u;
        }
        sboff[t] = v - orig;
    }
    __syncthreads();

    int wave = t >> 6, lane = t & 63;
    int n = blockIdx.x * 4 + wave;
    int sub = lane >> 5, cl = lane & 31;
    int c = cl * 8, h = cl >> 4;
    int beg = excl[n] + sboff[n >> 10];
    int end = (n + 1 < N_NODES) ? excl[n + 1] + sboff[(n + 1) >> 10] : N_EDGES;
    if (beg == end) {       // isolated node: h' = Wh
        if (sub == 0) {
            bf16x8 wh = *(const bf16x8*)(Wh + (size_t)n*F + c);
            f32x4 o0, o1;
            #pragma unroll
            for (int i = 0; i < 4; ++i) { o0[i] = (float)wh[i]; o1[i] = (float)wh[4+i]; }
            *(f32x4*)(out + (size_t)n*F + c)     = o0;
            *(f32x4*)(out + (size_t)n*F + c + 4) = o1;
        }
        return;
    }
    float2 sv = ((const float2*)s_arr)[n];
    float sum0 = 0.f, sum1 = 0.f;
    float a[8] = {0,0,0,0,0,0,0,0};
    float bacc[8] = {0,0,0,0,0,0,0,0};
    const float* sph = h ? sp1[wave] : sp0[wave];

    for (int c0 = beg; c0 < end; c0 += CAP) {
        int cnt = min(CAP, end - c0);
        // Phase A: fill p/d chunk (wave-local)
        for (int j = lane; j < cnt; j += 64) {
            int d = sdst[c0 + j];
            float2 tv = ((const float2*)t_arr)[d];
            float e0 = sv.x + tv.x; e0 = (e0 >= 0.f) ? e0 : 0.2f * e0;
            float e1 = sv.y + tv.y; e1 = (e1 >= 0.f) ? e1 : 0.2f * e1;
            float p0 = __expf(e0), p1 = __expf(e1);
            sp0[wave][j] = p0;
            sp1[wave][j] = p1;
            sd[wave][j]  = d;
            sum0 += p0;
            sum1 += p1;
        }
        // Phase B: gather + FMA (8 edges/iter, 4 per sub-slot)
        int j = 0;
        for (; j + 8 <= cnt; j += 8) {
            int j0 = j + sub, j1 = j + 2 + sub, j2 = j + 4 + sub, j3 = j + 6 + sub;
            int d0 = sd[wave][j0], d1 = sd[wave][j1];
            int d2 = sd[wave][j2], d3 = sd[wave][j3];
            float p0 = sph[j0], p1 = sph[j1], p2 = sph[j2], p3 = sph[j3];
            bf16x8 w0 = *(const bf16x8*)(Wh + (size_t)d0*F + c);
            bf16x8 w1 = *(const bf16x8*)(Wh + (size_t)d1*F + c);
            bf16x8 w2 = *(const bf16x8*)(Wh + (size_t)d2*F + c);
            bf16x8 w3 = *(const bf16x8*)(Wh + (size_t)d3*F + c);
            #pragma unroll
            for (int i = 0; i < 8; ++i) {
                a[i]    += p0 * (float)w0[i];
                bacc[i] += p1 * (float)w1[i];
                a[i]    += p2 * (float)w2[i];
                bacc[i] += p3 * (float)w3[i];
            }
        }
        for (; j < cnt; j += 2) {
            int jj = j + sub;
            int jc = (jj < cnt) ? jj : 0;
            float p = (jj < cnt) ? sph[jc] : 0.f;
            int d = sd[wave][jc];
            bf16x8 w = *(const bf16x8*)(Wh + (size_t)d*F + c);
            #pragma unroll
            for (int i = 0; i < 8; ++i) a[i] += p * (float)w[i];
        }
    }
    #pragma unroll
    for (int m = 32; m >= 1; m >>= 1) {
        sum0 += __shfl_xor(sum0, m);
        sum1 += __shfl_xor(sum1, m);
    }
    float inv = 1.f / (h ? sum1 : sum0);
    #pragma unroll
    for (int i = 0; i < 8; ++i) {
        a[i] += bacc[i];
        a[i] += __shfl_xor(a[i], 32);      // merge odd-slot partial
    }
    if (sub == 0) {
        f32x4 o0, o1;
        #pragma unroll
        for (int i = 0; i < 4; ++i) { o0[i] = a[i] * inv; o1[i] = a[4+i] * inv; }
        *(f32x4*)(out + (size_t)n*F + c)     = o0;
        *(f32x4*)(out + (size_t)n*F + c + 4) = o1;
    }
}

// ---------------- launch ----------------
extern "C" void kernel_launch(void* const* d_in, const int* in_sizes, int n_in,
                              void* d_out, int out_size, void* d_ws, size_t ws_size,
                              hipStream_t stream) {
    const float* x  = (const float*)d_in[0];
    const int*   ei = (const int*)d_in[1];
    const float* Ww = (const float*)d_in[2];
    const float* Wb = (const float*)d_in[3];
    const float* a  = (const float*)d_in[4];
    float* out = (float*)d_out;
    const int* src = ei;              // edge_index[0]
    const int* dst = ei + N_EDGES;    // edge_index[1]

    // workspace layout (~32 MB), 16B-aligned slices
    char* ws = (char*)d_ws;
    bf16*  Wh        = (bf16*)ws;   ws += (size_t)N_NODES * F * 2;       // 25.6 MB
    bf16*  Wt        = (bf16*)ws;   ws += (size_t)IN_DIM * F * 2;        // 128 KB
    float* s_arr     = (float*)ws;  ws += (size_t)N_NODES * 2 * 4;
    float* t_arr     = (float*)ws;  ws += (size_t)N_NODES * 2 * 4;
    int*   excl      = (int*)ws;    ws += (size_t)N_NODES * 4;
    int*   bsum      = (int*)ws;    ws += 64 * 4;
    unsigned short* prefix8 = (unsigned short*)ws; ws += (size_t)N_NODES * 8 * 2; // 800 KB
    unsigned char*  rank    = (unsigned char*)ws;  ws += (size_t)N_EDGES + 16;    // 800 KB
    int*   xcdtab    = (int*)ws;    ws += (size_t)NBLK_H * 4 + 12;       // pad to 16B
    int*   sdst      = (int*)ws;    ws += (size_t)N_EDGES * 4;           // 3.2 MB

    // deg8 (8 x N_NODES = 1.6 MB) ALIASES sdst: deg copies are consumed by
    // k_scan_local (disp 3) strictly before k_scatter writes sdst (disp 4).
    int* deg8 = sdst;

    k_transpose<<<IN_DIM, F, 0, stream>>>(Ww, Wt, deg8);
    k_gemm_hist<<<NBLK_FUSED, 256, 0, stream>>>(x, Wt, Wb, a, src, deg8, rank,
                                                xcdtab, Wh, s_arr, t_arr);
    k_scan_local<<<N_SB, SCAN_B, 0, stream>>>(deg8, excl, bsum, prefix8);
    k_scatter<<<NBLK_H, 256, 0, stream>>>(src, dst, rank, prefix8,
                                          excl, bsum, xcdtab, sdst);
    k_agg<<<N_NODES / 4, 256, 0, stream>>>(Wh, s_arr, t_arr, excl, bsum, sdst, out);
}